// Round 15
// baseline (1038.275 us; speedup 1.0000x reference)
//
#include <hip/hip_runtime.h>

typedef __attribute__((ext_vector_type(8))) short short8;
typedef __attribute__((ext_vector_type(4))) float f32x4;
typedef __attribute__((ext_vector_type(4))) float f4v;
typedef unsigned short u16;
typedef unsigned int u32;

#define NPTS 65536
#define CCH 512
#define GDIM 66
#define GDIM2 (66*66)
#define CAPO 18432          // per-offset compacted-row capacity
#define TPO1 144            // 128-row tiles per offset = CAPO/128

__device__ __forceinline__ u16 f2bf(float f) {            // RNE pack (precision-critical)
    u32 u = __builtin_bit_cast(u32, f);
    u32 r = (u + 0x7fffu + ((u >> 16) & 1u)) >> 16;
    return (u16)r;
}
__device__ __forceinline__ u16 f2bt(float f) {            // truncating pack (hot epilogues)
    return (u16)(__builtin_bit_cast(u32, f) >> 16);
}
__device__ __forceinline__ float bf2f(u16 h) {
    u32 u = ((u32)h) << 16;
    return __builtin_bit_cast(float, u);
}
// Fast transcendentals via proper intrinsics (inline-asm TRANS ops defeat the
// hazard recognizer -> replay nondeterminism; learned round 13).
__device__ __forceinline__ float fexp2(float x) { return __builtin_amdgcn_exp2f(x); }
__device__ __forceinline__ float frcp(float x)  { return __builtin_amdgcn_rcpf(x); }

__device__ __forceinline__ void gld16(const void* g, void* l) {
    __builtin_amdgcn_global_load_lds((const __attribute__((address_space(1))) void*)g,
                                     (__attribute__((address_space(3))) void*)l, 16, 0, 0);
}

// ============ counted-vmcnt single-barrier K-loop (BK=32, 3 bufs x 16KB) ============
// Per iter t: vmcnt(4) [tile t landed; tile t+1's 4 loads stay in flight] -> barrier
// -> stage tile t+2 -> ds_read buf[t%3] -> 16 MFMA. vmcnt never drains mid-loop.
// Swizzle (r7-verified, 0 conflicts): store chunk (tid&3) holds src chunk
// (tid&3)^((row>>1)&3); read chunk addr = (lane>>4)^((lane>>1)&3).
#define PIPE_LOOP(NT32)                                                                \
    stageT(0, 0); stageT(1, 1);                                                        \
    {                                                                                  \
        int cur = 0, sb = 2;                                                           \
        _Pragma("unroll 1")                                                            \
        for (int t = 0; t < (NT32); ++t) {                                             \
            __builtin_amdgcn_sched_barrier(0);                                         \
            if (t + 1 < (NT32)) asm volatile("s_waitcnt vmcnt(4)" ::: "memory");       \
            else                asm volatile("s_waitcnt vmcnt(0)" ::: "memory");       \
            __builtin_amdgcn_s_barrier();                                              \
            __builtin_amdgcn_sched_barrier(0);                                         \
            if (t + 2 < (NT32)) { stageT(sb, t + 2); sb = (sb == 2) ? 0 : sb + 1; }    \
            const char* la = lds + cur * 16384;                                        \
            const char* lb = la + 8192;                                                \
            cur = (cur == 2) ? 0 : cur + 1;                                            \
            short8 a[4], b[4];                                                         \
            _Pragma("unroll")                                                          \
            for (int f = 0; f < 4; ++f) {                                              \
                a[f] = *(const short8*)(const void*)(la + (wm*64 + f*16 + rbase)*64 + chx*16); \
                b[f] = *(const short8*)(const void*)(lb + (wn*64 + f*16 + rbase)*64 + chx*16); \
            }                                                                          \
            __builtin_amdgcn_s_setprio(1);                                             \
            _Pragma("unroll")                                                          \
            for (int i = 0; i < 4; ++i)                                                \
                _Pragma("unroll")                                                      \
                for (int j = 0; j < 4; ++j)                                            \
                    acc[i][j] = __builtin_amdgcn_mfma_f32_16x16x32_bf16(a[i], b[j], acc[i][j], 0, 0, 0); \
            __builtin_amdgcn_s_setprio(0);                                             \
        }                                                                              \
    }

// ---------------- setup kernels ----------------

__global__ void scatter_vox(const int* __restrict__ coords, int* __restrict__ grid) {
    int i = blockIdx.x * 256 + threadIdx.x;
    if (i < NPTS) {
        int c0 = coords[3*i], c1 = coords[3*i+1], c2 = coords[3*i+2];
        grid[(c0+1)*GDIM2 + (c1+1)*GDIM + (c2+1)] = i;
    }
}

__global__ void cast_bf16(const float* __restrict__ in, u16* __restrict__ out, int n8) {
    int i = blockIdx.x * 256 + threadIdx.x;
    if (i >= n8) return;
    f4v a = *(const f4v*)(in + (size_t)i*8);
    f4v b = *(const f4v*)(in + (size_t)i*8 + 4);
    short8 o;
    #pragma unroll
    for (int j = 0; j < 4; ++j) { o[j] = (short)f2bf(a[j]); o[j+4] = (short)f2bf(b[j]); }
    *(short8*)(out + (size_t)i*8) = o;
}

// in: f32 [R][Cc] row-major, out: bf16 [Cc][R]
__global__ void transpose_cast(const float* __restrict__ in, u16* __restrict__ out,
                               int R, int Cc) {
    __shared__ float tile[32][33];
    size_t moff = (size_t)blockIdx.z * R * Cc;
    in += moff; out += moff;
    int tx = threadIdx.x, ty = threadIdx.y;
    #pragma unroll
    for (int j = 0; j < 4; ++j) {
        int r = blockIdx.y*32 + ty + j*8;
        int c = blockIdx.x*32 + tx;
        tile[ty + j*8][tx] = in[(size_t)r*Cc + c];
    }
    __syncthreads();
    #pragma unroll
    for (int j = 0; j < 4; ++j) {
        int orow = blockIdx.x*32 + ty + j*8;
        int ocol = blockIdx.y*32 + tx;
        out[(size_t)orow*R + ocol] = f2bf(tile[tx][ty + j*8]);
    }
}

// ---------------- compaction: count -> scan -> fill (+ inverse posMap) ----------------

__device__ __forceinline__ int nbr_lookup(const int* coords, const int* grid, int i, int o) {
    int dx = o / 9, dy = (o / 3) % 3, dz = o % 3;
    int c0 = coords[3*i], c1 = coords[3*i+1], c2 = coords[3*i+2];
    return grid[(c0+dx)*GDIM2 + (c1+dy)*GDIM + (c2+dz)];
}

__global__ __launch_bounds__(256) void count_valid(const int* __restrict__ coords,
        const int* __restrict__ grid, int* __restrict__ blockCnt) {
    int o1 = blockIdx.y;
    int o = o1 + (o1 >= 13);
    int i = blockIdx.x*256 + threadIdx.x;
    int v = nbr_lookup(coords, grid, i, o);
    unsigned long long b = __ballot(v >= 0);
    __shared__ int wc[4];
    if ((threadIdx.x & 63) == 0) wc[threadIdx.x >> 6] = __popcll(b);
    __syncthreads();
    if (threadIdx.x == 0)
        blockCnt[o1*256 + blockIdx.x] = wc[0]+wc[1]+wc[2]+wc[3];
}

// one block per offset (26 blocks)
__global__ __launch_bounds__(256) void scan_kernel(const int* __restrict__ blockCnt,
        int* __restrict__ blockOff, int* __restrict__ cnt) {
    int o1 = blockIdx.x;
    int t = threadIdx.x, lane = t & 63, w = t >> 6;
    __shared__ int wsum[4];
    int v = blockCnt[o1*256 + t];
    int x = v;
    #pragma unroll
    for (int s = 1; s < 64; s <<= 1) {
        int y = __shfl_up(x, s);
        if (lane >= s) x += y;
    }
    if (lane == 63) wsum[w] = x;
    __syncthreads();
    int base = 0;
    for (int k = 0; k < w; ++k) base += wsum[k];
    blockOff[o1*256 + t] = base + x - v;
    if (t == 255) cnt[o1] = base + x;
}

__global__ __launch_bounds__(256) void fill_kernel(const int* __restrict__ coords,
        const int* __restrict__ grid, const int* __restrict__ blockOff,
        int* __restrict__ srcIdx, int* __restrict__ posMap) {
    int o1 = blockIdx.y;
    int o = o1 + (o1 >= 13);
    int i = blockIdx.x*256 + threadIdx.x;
    int v = nbr_lookup(coords, grid, i, o);
    bool valid = v >= 0;
    unsigned long long b = __ballot(valid);
    int lane = threadIdx.x & 63, w = threadIdx.x >> 6;
    __shared__ int wc[4];
    if (lane == 0) wc[w] = __popcll(b);
    __syncthreads();
    int base = blockOff[o1*256 + blockIdx.x];
    for (int k = 0; k < w; ++k) base += wc[k];
    int pre = __popcll(b & ((1ull << lane) - 1ull));
    int pos = base + pre;
    bool ok = valid && pos < CAPO;
    if (ok) srcIdx[o1*CAPO + pos] = v;
    posMap[(size_t)o1*NPTS + i] = ok ? pos : -1;
}

// ============ 128x128 GEMM, pipelined engine (see PIPE_LOOP) ============
// MODE 1: mlp1 — outb bf16 = silu(acc+bias)
// MODE 2: mlp2 — outf f32 = acc+bias+resid (RES=1: bf16 fbres, RES=0: f32 fres)
// MODE 3: conv center — outb bf16 = acc+bias
// LDOUT: compile-time output leading dim. XCD-grouped block map.

template<int MODE, int NX, int RES, int LDOUT>
__global__ __launch_bounds__(256, 3) void gemm128(
    const u16* __restrict__ A, int lda,
    const u16* __restrict__ BT, int ldb,
    int nT32,
    const float* __restrict__ bias,
    const u16* __restrict__ fbres,
    const float* __restrict__ fres,
    float* __restrict__ outf, u16* __restrict__ outb)
{
    __shared__ __align__(1024) char lds[49152];   // 3 bufs x (A 8KB + B 8KB)
    const int L = blockIdx.x;
    const int cx = L & 7, tt0 = L >> 3;
    const int bx = tt0 % NX;
    const int by = cx + 8 * (tt0 / NX);
    const int row0 = by * 128, col0 = bx * 128;

    const int tid = threadIdx.x;
    const int w = tid >> 6, lane = tid & 63;
    const int wm = w >> 1, wn = w & 1;
    const int rI = tid >> 2;                           // 0..63
    const int csrc = (tid & 3) ^ ((tid >> 3) & 3);     // source chunk (inverse swizzle)
    const int rbase = lane & 15;
    const int chx = (lane >> 4) ^ ((lane >> 1) & 3);   // read-side swizzled chunk

    f32x4 acc[4][4] = {};

    const u16* aP0 = A + (size_t)(row0 + rI) * lda + csrc*8;
    const u16* aP1 = aP0 + (size_t)64 * lda;
    const u16* bP0 = BT + (size_t)(col0 + rI) * ldb + csrc*8;
    const u16* bP1 = bP0 + (size_t)64 * ldb;

    auto stageT = [&](int buf, int tt) {
        char* la = lds + buf*16384;
        int k0 = tt * 32;
        gld16(aP0 + k0, la + tid*16);
        gld16(aP1 + k0, la + 4096 + tid*16);
        gld16(bP0 + k0, la + 8192 + tid*16);
        gld16(bP1 + k0, la + 12288 + tid*16);
    };

    PIPE_LOOP(nT32)

    #pragma unroll
    for (int i = 0; i < 4; ++i) {
        int r = row0 + wm*64 + i*16 + (lane >> 4)*4;
        #pragma unroll
        for (int j = 0; j < 4; ++j) {
            int c = col0 + wn*64 + j*16 + (lane & 15);
            float bv = bias[c];
            #pragma unroll
            for (int q = 0; q < 4; ++q) {
                float v = acc[i][j][q];
                if constexpr (MODE == 1) {
                    float val = v + bv;
                    float sg = frcp(1.f + fexp2(val * -1.44269504f));
                    outb[(size_t)(r+q)*LDOUT + c] = f2bt(val * sg);
                } else if constexpr (MODE == 2) {
                    size_t ix = (size_t)(r+q)*LDOUT + c;
                    float rsd = RES ? bf2f(fbres[ix]) : fres[ix];
                    outf[ix] = v + bv + rsd;
                } else {  // MODE 3
                    outb[(size_t)(r+q)*LDOUT + c] = f2bt(v + bv);
                }
            }
        }
    }
}

// comp GEMM: compacted rows -> bf16 contribution rows (no atomics), same engine.
__global__ __launch_bounds__(256, 3) void comp_gemm(
    const u16* __restrict__ fb,
    const int* __restrict__ srcIdx,
    const int* __restrict__ cnt,
    const u16* __restrict__ wcT,
    u16* __restrict__ comp,
    int o1base)
{
    __shared__ __align__(1024) char lds[49152];
    const int L = blockIdx.x;
    const int cx = L & 7, tt0 = L >> 3;
    const int bx = tt0 & 3;                 // col tile (4 x 128)
    const int y  = cx + 8 * (tt0 >> 2);
    const int o1loc = y / TPO1, mt = y % TPO1;
    const int o1 = o1base + o1loc;
    const int n = cnt[o1];
    if (mt * 128 >= n) return;              // block-uniform, before any barrier
    const int o = o1 + (o1 >= 13);
    const int tid = threadIdx.x;
    const int w = tid >> 6, lane = tid & 63;
    const int wm = w >> 1, wn = w & 1;
    const int col0 = bx * 128;
    const int rI = tid >> 2;
    const int csrc = (tid & 3) ^ ((tid >> 3) & 3);
    const int rbase = lane & 15;
    const int chx = (lane >> 4) ^ ((lane >> 1) & 3);

    const int* sIdx = srcIdx + o1*CAPO + mt*128;
    const u16* wb = wcT + ((size_t)o << 18);

    int src0 = (mt*128 + rI      < n) ? sIdx[rI]      : NPTS;   // zero-row fallback
    int src1 = (mt*128 + 64 + rI < n) ? sIdx[64 + rI] : NPTS;
    const u16* aP0 = fb + (size_t)src0*512 + csrc*8;
    const u16* aP1 = fb + (size_t)src1*512 + csrc*8;
    const u16* bP0 = wb + (size_t)(col0 + rI)*512 + csrc*8;
    const u16* bP1 = bP0 + (size_t)64*512;

    f32x4 acc[4][4] = {};

    auto stageT = [&](int buf, int tt) {
        char* la = lds + buf*16384;
        int k0 = tt * 32;
        gld16(aP0 + k0, la + tid*16);
        gld16(aP1 + k0, la + 4096 + tid*16);
        gld16(bP0 + k0, la + 8192 + tid*16);
        gld16(bP1 + k0, la + 12288 + tid*16);
    };

    PIPE_LOOP(16)

    #pragma unroll
    for (int i = 0; i < 4; ++i) {
        #pragma unroll
        for (int q = 0; q < 4; ++q) {
            int rl = wm*64 + i*16 + (lane >> 4)*4 + q;
            if (mt*128 + rl < n) {
                u16* cr = comp + ((size_t)(o1loc*CAPO + mt*128 + rl))*512
                               + col0 + wn*64 + (lane & 15);
                #pragma unroll
                for (int j = 0; j < 4; ++j)
                    cr[j*16] = f2bt(acc[i][j][q]);
            }
        }
    }
}

// ---------------- gather-reduce: hc(bf16) += contributions; FINAL fuses LN -> nf ------

template<int FINAL>
__global__ __launch_bounds__(512) void reduce_kernel(
    const u16* __restrict__ comp, const int* __restrict__ posMap,
    int o1base, int nOff,
    u16* __restrict__ hc,
    const float* __restrict__ g, const float* __restrict__ bb,
    u16* __restrict__ nf)
{
    int w = threadIdx.x >> 6, lane = threadIdx.x & 63;
    int i = blockIdx.x*8 + w;
    u16* hr = hc + (size_t)i*512 + lane*8;
    short8 hv = *(const short8*)hr;
    float x[8];
    #pragma unroll
    for (int j = 0; j < 8; ++j) x[j] = bf2f((u16)hv[j]);

    #pragma unroll 1
    for (int k = 0; k < nOff; ++k) {
        int pos = posMap[(size_t)(o1base + k)*NPTS + i];
        if (pos >= 0) {   // wave-uniform branch
            short8 cv = *(const short8*)(comp + ((size_t)k*CAPO + pos)*512 + lane*8);
            #pragma unroll
            for (int j = 0; j < 8; ++j) x[j] += bf2f((u16)cv[j]);
        }
    }

    if constexpr (!FINAL) {
        short8 o;
        #pragma unroll
        for (int j = 0; j < 8; ++j) o[j] = (short)f2bf(x[j]);
        *(short8*)hr = o;
    } else {
        float s = 0.f, ss = 0.f;
        #pragma unroll
        for (int j = 0; j < 8; ++j) { s += x[j]; ss += x[j]*x[j]; }
        #pragma unroll
        for (int m = 1; m < 64; m <<= 1) { s += __shfl_xor(s, m); ss += __shfl_xor(ss, m); }
        float mu = s * (1.f/512.f);
        float var = ss * (1.f/512.f) - mu*mu;
        float inv = rsqrtf(var + 1e-6f);
        short8 o;
        #pragma unroll
        for (int j = 0; j < 8; ++j) {
            int c = lane*8 + j;
            o[j] = (short)f2bf((x[j] - mu) * inv * g[c] + bb[c]);
        }
        *(short8*)(nf + (size_t)i*512 + lane*8) = o;
    }
}

// ---------------- launch ----------------

extern "C" void kernel_launch(void* const* d_in, const int* in_sizes, int n_in,
                              void* d_out, int out_size, void* d_ws, size_t ws_size,
                              hipStream_t stream) {
    const float* feats  = (const float*)d_in[0];
    const int*   coords = (const int*)d_in[1];
    const float* conv_w = (const float*)d_in[2];
    const float* conv_b = (const float*)d_in[3];
    const float* ln_g   = (const float*)d_in[4];
    const float* ln_b   = (const float*)d_in[5];
    const float* w1     = (const float*)d_in[6];
    const float* b1     = (const float*)d_in[7];
    const float* w2     = (const float*)d_in[8];
    const float* b2     = (const float*)d_in[9];
    float* out = (float*)d_out;
    char* ws = (char*)d_ws;

    size_t off = 0;
    auto take = [&](size_t bytes) -> void* {
        void* p = ws + off;
        off += (bytes + 1023) & ~(size_t)1023;
        return p;
    };
    int* grid_i   = (int*)take((size_t)GDIM*GDIM2*4);
    u16* wcT      = (u16*)take(27ull*512*512*2);
    u16* w1T      = (u16*)take(2048ull*512*2);
    u16* w2T      = (u16*)take(512ull*2048*2);
    u16* fb       = (u16*)take((NPTS+1ull)*512*2);  // cast feats
    int* srcIdx   = (int*)take(26ull*CAPO*4);
    int* posMap   = (int*)take(26ull*NPTS*4);
    int* blockCnt = (int*)take(26*256*4);
    int* blockOff = (int*)take(26*256*4);
    int* cnt      = (int*)take(26*4);

    const size_t nf_b     = 67108864ull;           // bf16 [N][512]
    const size_t comp13_b = 13ull*CAPO*512*2;      // 245.4 MB
    const size_t hc_b     = 67108864ull;           // bf16 [N][512]
    const size_t slack    = 65536;

    // Layout A: separate nf (fb stays intact -> bf16 residual). Needs +64MB.
    bool sepNF = (off + nf_b + comp13_b + hc_b + slack) <= ws_size;

    u16* nf   = sepNF ? (u16*)take(nf_b) : fb;     // Layout B: nf aliases fb (f32 resid)
    u16* comp = (u16*)take(comp13_b);
    u16* hc   = (u16*)take(hc_b);
    u16* g1   = comp;   // [N][2048] overlays comp(245MB)+hc(64MB): both dead after reduce<1>

    hipMemsetAsync(grid_i, 0xFF, (size_t)GDIM*GDIM2*4, stream);
    hipMemsetAsync(fb + (size_t)NPTS*512, 0, 512*2, stream);

    scatter_vox<<<NPTS/256, 256, 0, stream>>>(coords, grid_i);
    cast_bf16<<<(NPTS*CCH/8)/256, 256, 0, stream>>>(feats, fb, NPTS*CCH/8);
    transpose_cast<<<dim3(16,16,27), dim3(32,8), 0, stream>>>(conv_w, wcT, 512, 512);
    transpose_cast<<<dim3(64,16,1),  dim3(32,8), 0, stream>>>(w1, w1T, 512, 2048);
    transpose_cast<<<dim3(16,64,1),  dim3(32,8), 0, stream>>>(w2, w2T, 2048, 512);

    count_valid<<<dim3(256,26), 256, 0, stream>>>(coords, grid_i, blockCnt);
    scan_kernel<<<26, 256, 0, stream>>>(blockCnt, blockOff, cnt);
    fill_kernel<<<dim3(256,26), 256, 0, stream>>>(coords, grid_i, blockOff, srcIdx, posMap);

    // center offset (o=13): dense, writes hc bf16 = fb @ W13^T + conv_b
    gemm128<3,4,0,512><<<2048, 256, 0, stream>>>(
        fb, 512, wcT + (13ull << 18), 512, 16, conv_b,
        nullptr, nullptr, nullptr, hc);

    // two passes of 13 non-center offsets: compact GEMM -> gather reduce (no atomics)
    comp_gemm<<<4*TPO1*13, 256, 0, stream>>>(fb, srcIdx, cnt, wcT, comp, 0);
    reduce_kernel<0><<<NPTS/8, 512, 0, stream>>>(comp, posMap, 0, 13, hc, nullptr, nullptr, nullptr);
    comp_gemm<<<4*TPO1*13, 256, 0, stream>>>(fb, srcIdx, cnt, wcT, comp, 13);
    reduce_kernel<1><<<NPTS/8, 512, 0, stream>>>(comp, posMap, 13, 13, hc, ln_g, ln_b, nf);

    // MLP1 fused: one launch over all 2048 hidden cols -> g1 [N][2048] (overlays comp+hc)
    gemm128<1,16,0,2048><<<8192, 256, 0, stream>>>(
        nf, 512, w1T, 512, 16, b1, nullptr, nullptr, nullptr, g1);

    // MLP2 fused: single K=2048 launch, writes out once
    if (sepNF) {
        gemm128<2,4,1,512><<<2048, 256, 0, stream>>>(
            g1, 2048, w2T, 2048, 64, b2, fb, nullptr, out, nullptr);
    } else {
        gemm128<2,4,0,512><<<2048, 256, 0, stream>>>(
            g1, 2048, w2T, 2048, 64, b2, nullptr, feats, out, nullptr);
    }
}

// Round 16
// 896.138 us; speedup vs baseline: 1.1586x; 1.1586x over previous
//
#include <hip/hip_runtime.h>

typedef __attribute__((ext_vector_type(8))) short short8;
typedef __attribute__((ext_vector_type(4))) float f32x4;
typedef __attribute__((ext_vector_type(4))) float f4v;
typedef unsigned short u16;
typedef unsigned int u32;

#define NPTS 65536
#define CCH 512
#define GDIM 66
#define GDIM2 (66*66)
#define CAPO 18432          // per-offset compacted-row capacity
#define TPO1 144            // 128-row tiles per offset = CAPO/128

__device__ __forceinline__ u16 f2bf(float f) {            // RNE pack (precision-critical)
    u32 u = __builtin_bit_cast(u32, f);
    u32 r = (u + 0x7fffu + ((u >> 16) & 1u)) >> 16;
    return (u16)r;
}
__device__ __forceinline__ u16 f2bt(float f) {            // truncating pack (hot epilogues)
    return (u16)(__builtin_bit_cast(u32, f) >> 16);
}
__device__ __forceinline__ float bf2f(u16 h) {
    u32 u = ((u32)h) << 16;
    return __builtin_bit_cast(float, u);
}
// Fast transcendentals via proper intrinsics (inline-asm TRANS ops defeat the
// hazard recognizer -> replay nondeterminism; learned round 13).
__device__ __forceinline__ float fexp2(float x) { return __builtin_amdgcn_exp2f(x); }
__device__ __forceinline__ float frcp(float x)  { return __builtin_amdgcn_rcpf(x); }

__device__ __forceinline__ void gld16(const void* g, void* l) {
    __builtin_amdgcn_global_load_lds((const __attribute__((address_space(1))) void*)g,
                                     (__attribute__((address_space(3))) void*)l, 16, 0, 0);
}

// ---------------- setup kernels ----------------

// cast feats f32->bf16; first NPTS threads also scatter point ids into the voxel grid
__global__ void cast_scatter(const float* __restrict__ in, u16* __restrict__ out,
                             const int* __restrict__ coords, int* __restrict__ grid) {
    int i = blockIdx.x * 256 + threadIdx.x;
    if (i < NPTS) {
        int c0 = coords[3*i], c1 = coords[3*i+1], c2 = coords[3*i+2];
        grid[(c0+1)*GDIM2 + (c1+1)*GDIM + (c2+1)] = i;
    }
    f4v a = *(const f4v*)(in + (size_t)i*8);
    f4v b = *(const f4v*)(in + (size_t)i*8 + 4);
    short8 o;
    #pragma unroll
    for (int j = 0; j < 4; ++j) { o[j] = (short)f2bf(a[j]); o[j+4] = (short)f2bf(b[j]); }
    *(short8*)(out + (size_t)i*8) = o;
}

// in: f32 [R][Cc] row-major, out: bf16 [Cc][R]
__global__ void transpose_cast(const float* __restrict__ in, u16* __restrict__ out,
                               int R, int Cc) {
    __shared__ float tile[32][33];
    size_t moff = (size_t)blockIdx.z * R * Cc;
    in += moff; out += moff;
    int tx = threadIdx.x, ty = threadIdx.y;
    #pragma unroll
    for (int j = 0; j < 4; ++j) {
        int r = blockIdx.y*32 + ty + j*8;
        int c = blockIdx.x*32 + tx;
        tile[ty + j*8][tx] = in[(size_t)r*Cc + c];
    }
    __syncthreads();
    #pragma unroll
    for (int j = 0; j < 4; ++j) {
        int orow = blockIdx.x*32 + ty + j*8;
        int ocol = blockIdx.y*32 + tx;
        out[(size_t)orow*R + ocol] = f2bf(tile[tx][ty + j*8]);
    }
}

// ---------------- compaction: count -> scan -> fill (+ inverse posMap) ----------------

__device__ __forceinline__ int nbr_lookup(const int* coords, const int* grid, int i, int o) {
    int dx = o / 9, dy = (o / 3) % 3, dz = o % 3;
    int c0 = coords[3*i], c1 = coords[3*i+1], c2 = coords[3*i+2];
    return grid[(c0+dx)*GDIM2 + (c1+dy)*GDIM + (c2+dz)];
}

__global__ __launch_bounds__(256) void count_valid(const int* __restrict__ coords,
        const int* __restrict__ grid, int* __restrict__ blockCnt) {
    int o1 = blockIdx.y;
    int o = o1 + (o1 >= 13);
    int i = blockIdx.x*256 + threadIdx.x;
    int v = nbr_lookup(coords, grid, i, o);
    unsigned long long b = __ballot(v >= 0);
    __shared__ int wc[4];
    if ((threadIdx.x & 63) == 0) wc[threadIdx.x >> 6] = __popcll(b);
    __syncthreads();
    if (threadIdx.x == 0)
        blockCnt[o1*256 + blockIdx.x] = wc[0]+wc[1]+wc[2]+wc[3];
}

// one block per offset (26 blocks)
__global__ __launch_bounds__(256) void scan_kernel(const int* __restrict__ blockCnt,
        int* __restrict__ blockOff, int* __restrict__ cnt) {
    int o1 = blockIdx.x;
    int t = threadIdx.x, lane = t & 63, w = t >> 6;
    __shared__ int wsum[4];
    int v = blockCnt[o1*256 + t];
    int x = v;
    #pragma unroll
    for (int s = 1; s < 64; s <<= 1) {
        int y = __shfl_up(x, s);
        if (lane >= s) x += y;
    }
    if (lane == 63) wsum[w] = x;
    __syncthreads();
    int base = 0;
    for (int k = 0; k < w; ++k) base += wsum[k];
    blockOff[o1*256 + t] = base + x - v;
    if (t == 255) cnt[o1] = base + x;
}

__global__ __launch_bounds__(256) void fill_kernel(const int* __restrict__ coords,
        const int* __restrict__ grid, const int* __restrict__ blockOff,
        int* __restrict__ srcIdx, int* __restrict__ posMap) {
    int o1 = blockIdx.y;
    int o = o1 + (o1 >= 13);
    int i = blockIdx.x*256 + threadIdx.x;
    int v = nbr_lookup(coords, grid, i, o);
    bool valid = v >= 0;
    unsigned long long b = __ballot(valid);
    int lane = threadIdx.x & 63, w = threadIdx.x >> 6;
    __shared__ int wc[4];
    if (lane == 0) wc[w] = __popcll(b);
    __syncthreads();
    int base = blockOff[o1*256 + blockIdx.x];
    for (int k = 0; k < w; ++k) base += wc[k];
    int pre = __popcll(b & ((1ull << lane) - 1ull));
    int pos = base + pre;
    bool ok = valid && pos < CAPO;
    if (ok) srcIdx[o1*CAPO + pos] = v;
    posMap[(size_t)o1*NPTS + i] = ok ? pos : -1;
}

// ============ m97-style 128x128 GEMM engine: 4 waves, 32KB LDS, 2 barriers/K-step ====
// __launch_bounds__(256,4): VGPR~60 + 64 AGPR acc, no spill. (Pipelined variants
// tried rounds 6/7/15: all neutral-to-regression — implicit inter-block overlap
// at 4 blocks/CU beats manual vmcnt pipelines for these short-K GEMMs.)
// MODE 1: mlp1 — outb bf16 = silu(acc+bias)   [fast sigmoid + trunc pack]
// MODE 2: mlp2 — outf f32 = acc+bias+resid (RES=1: bf16 fbres, RES=0: f32 fres)
// MODE 3: conv center — outb bf16 = acc+bias  [trunc pack]
// LDOUT: compile-time output leading dim. XCD-grouped block map.

template<int MODE, int NX, int RES, int LDOUT>
__global__ __launch_bounds__(256, 4) void gemm128(
    const u16* __restrict__ A, int lda,
    const u16* __restrict__ BT, int ldb,
    int nT,
    const float* __restrict__ bias,
    const u16* __restrict__ fbres,
    const float* __restrict__ fres,
    float* __restrict__ outf, u16* __restrict__ outb)
{
    __shared__ __align__(1024) char ldsA[16384];
    __shared__ __align__(1024) char ldsB[16384];
    const int L = blockIdx.x;
    const int cx = L & 7, tt0 = L >> 3;
    const int bx = tt0 % NX;
    const int by = cx + 8 * (tt0 / NX);
    const int row0 = by * 128, col0 = bx * 128;

    const int t = threadIdx.x;
    const int w = t >> 6, lane = t & 63;
    const int wm = w >> 1, wn = w & 1;
    const int ccsrc = (lane & 7) ^ (lane >> 3);
    const int laneRow = lane >> 3;

    f32x4 acc[4][4] = {};

    const u16* aptr[4];
    const u16* bptr[4];
    #pragma unroll
    for (int it = 0; it < 4; ++it) {
        int r = w*32 + it*8 + laneRow;
        aptr[it] = A + (size_t)(row0 + r)*lda + ccsrc*8;
        bptr[it] = BT + (size_t)(col0 + r)*ldb + ccsrc*8;
    }

    #pragma unroll 1
    for (int ks = 0; ks < nT; ++ks) {
        int k0 = ks * 64;
        #pragma unroll
        for (int it = 0; it < 4; ++it) {
            int c = w*256 + it*64 + lane;
            gld16(aptr[it] + k0, ldsA + c*16);
            gld16(bptr[it] + k0, ldsB + c*16);
        }
        __syncthreads();
        #pragma unroll
        for (int kk = 0; kk < 2; ++kk) {
            short8 a[4], b[4];
            #pragma unroll
            for (int f = 0; f < 4; ++f) {
                int rowA = wm*64 + f*16 + (lane & 15);
                int ch = (kk*4 + (lane >> 4)) ^ (lane & 7);
                a[f] = *(const short8*)(void*)(ldsA + rowA*128 + ch*16);
                int rowB = wn*64 + f*16 + (lane & 15);
                b[f] = *(const short8*)(void*)(ldsB + rowB*128 + ch*16);
            }
            #pragma unroll
            for (int i = 0; i < 4; ++i)
                #pragma unroll
                for (int j = 0; j < 4; ++j)
                    acc[i][j] = __builtin_amdgcn_mfma_f32_16x16x32_bf16(a[i], b[j], acc[i][j], 0, 0, 0);
        }
        __syncthreads();
    }

    #pragma unroll
    for (int i = 0; i < 4; ++i) {
        int r = row0 + wm*64 + i*16 + (lane >> 4)*4;
        #pragma unroll
        for (int j = 0; j < 4; ++j) {
            int c = col0 + wn*64 + j*16 + (lane & 15);
            float bv = bias[c];
            #pragma unroll
            for (int q = 0; q < 4; ++q) {
                float v = acc[i][j][q];
                if constexpr (MODE == 1) {
                    float val = v + bv;
                    float sg = frcp(1.f + fexp2(val * -1.44269504f));
                    outb[(size_t)(r+q)*LDOUT + c] = f2bt(val * sg);
                } else if constexpr (MODE == 2) {
                    size_t ix = (size_t)(r+q)*LDOUT + c;
                    float rsd = RES ? bf2f(fbres[ix]) : fres[ix];
                    outf[ix] = v + bv + rsd;
                } else {  // MODE 3
                    outb[(size_t)(r+q)*LDOUT + c] = f2bt(v + bv);
                }
            }
        }
    }
}

// comp GEMM: compacted rows -> bf16 contribution rows (no atomics), 128x128 engine.
__global__ __launch_bounds__(256, 4) void comp_gemm(
    const u16* __restrict__ fb,
    const int* __restrict__ srcIdx,
    const int* __restrict__ cnt,
    const u16* __restrict__ wcT,
    u16* __restrict__ comp,
    int o1base)
{
    __shared__ __align__(1024) char ldsA[16384];
    __shared__ __align__(1024) char ldsB[16384];
    const int L = blockIdx.x;
    const int cx = L & 7, tt0 = L >> 3;
    const int bx = tt0 & 3;                 // col tile (4 x 128)
    const int y  = cx + 8 * (tt0 >> 2);
    const int o1loc = y / TPO1, mt = y % TPO1;
    const int o1 = o1base + o1loc;
    const int n = cnt[o1];
    if (mt * 128 >= n) return;              // block-uniform, before any barrier
    const int o = o1 + (o1 >= 13);
    const int t = threadIdx.x;
    const int w = t >> 6, lane = t & 63;
    const int wm = w >> 1, wn = w & 1;
    const int col0 = bx * 128;
    const int ccsrc = (lane & 7) ^ (lane >> 3);
    const int laneRow = lane >> 3;

    const int* sIdx = srcIdx + o1*CAPO + mt*128;
    const u16* wb = wcT + ((size_t)o << 18);

    const u16* aptr[4];
    const u16* bptr[4];
    #pragma unroll
    for (int it = 0; it < 4; ++it) {
        int rloc = w*32 + it*8 + laneRow;
        int src = (mt*128 + rloc < n) ? sIdx[rloc] : NPTS;   // zero-row fallback
        aptr[it] = fb + (size_t)src*512 + ccsrc*8;
        bptr[it] = wb + (size_t)(col0 + rloc)*512 + ccsrc*8;
    }

    f32x4 acc[4][4] = {};

    #pragma unroll 1
    for (int ks = 0; ks < 8; ++ks) {
        int k0 = ks * 64;
        #pragma unroll
        for (int it = 0; it < 4; ++it) {
            int c = w*256 + it*64 + lane;
            gld16(aptr[it] + k0, ldsA + c*16);
            gld16(bptr[it] + k0, ldsB + c*16);
        }
        __syncthreads();
        #pragma unroll
        for (int kk = 0; kk < 2; ++kk) {
            short8 a[4], b[4];
            #pragma unroll
            for (int f = 0; f < 4; ++f) {
                int rowA = wm*64 + f*16 + (lane & 15);
                int ch = (kk*4 + (lane >> 4)) ^ (lane & 7);
                a[f] = *(const short8*)(void*)(ldsA + rowA*128 + ch*16);
                int rowB = wn*64 + f*16 + (lane & 15);
                b[f] = *(const short8*)(void*)(ldsB + rowB*128 + ch*16);
            }
            #pragma unroll
            for (int i = 0; i < 4; ++i)
                #pragma unroll
                for (int j = 0; j < 4; ++j)
                    acc[i][j] = __builtin_amdgcn_mfma_f32_16x16x32_bf16(a[i], b[j], acc[i][j], 0, 0, 0);
        }
        __syncthreads();
    }

    #pragma unroll
    for (int i = 0; i < 4; ++i) {
        #pragma unroll
        for (int q = 0; q < 4; ++q) {
            int rl = wm*64 + i*16 + (lane >> 4)*4 + q;
            if (mt*128 + rl < n) {
                u16* cr = comp + ((size_t)(o1loc*CAPO + mt*128 + rl))*512
                               + col0 + wn*64 + (lane & 15);
                #pragma unroll
                for (int j = 0; j < 4; ++j)
                    cr[j*16] = f2bt(acc[i][j][q]);
            }
        }
    }
}

// ---------------- gather-reduce: hc(bf16) += contributions; FINAL fuses LN -> nf ------
// posMap entries prefetched up-front: 13 independent loads issue before the serial
// gather loop (breaks the dependent-load latency chain).

template<int FINAL>
__global__ __launch_bounds__(512) void reduce_kernel(
    const u16* __restrict__ comp, const int* __restrict__ posMap,
    int o1base, int nOff,
    u16* __restrict__ hc,
    const float* __restrict__ g, const float* __restrict__ bb,
    u16* __restrict__ nf)
{
    int w = threadIdx.x >> 6, lane = threadIdx.x & 63;
    int i = blockIdx.x*8 + w;

    int pos[13];
    #pragma unroll
    for (int k = 0; k < 13; ++k)
        pos[k] = (k < nOff) ? posMap[(size_t)(o1base + k)*NPTS + i] : -1;

    u16* hr = hc + (size_t)i*512 + lane*8;
    short8 hv = *(const short8*)hr;
    float x[8];
    #pragma unroll
    for (int j = 0; j < 8; ++j) x[j] = bf2f((u16)hv[j]);

    #pragma unroll 1
    for (int k = 0; k < nOff; ++k) {
        if (pos[k] >= 0) {   // wave-uniform branch
            short8 cv = *(const short8*)(comp + ((size_t)k*CAPO + pos[k])*512 + lane*8);
            #pragma unroll
            for (int j = 0; j < 8; ++j) x[j] += bf2f((u16)cv[j]);
        }
    }

    if constexpr (!FINAL) {
        short8 o;
        #pragma unroll
        for (int j = 0; j < 8; ++j) o[j] = (short)f2bf(x[j]);
        *(short8*)hr = o;
    } else {
        float s = 0.f, ss = 0.f;
        #pragma unroll
        for (int j = 0; j < 8; ++j) { s += x[j]; ss += x[j]*x[j]; }
        #pragma unroll
        for (int m = 1; m < 64; m <<= 1) { s += __shfl_xor(s, m); ss += __shfl_xor(ss, m); }
        float mu = s * (1.f/512.f);
        float var = ss * (1.f/512.f) - mu*mu;
        float inv = rsqrtf(var + 1e-6f);
        short8 o;
        #pragma unroll
        for (int j = 0; j < 8; ++j) {
            int c = lane*8 + j;
            o[j] = (short)f2bf((x[j] - mu) * inv * g[c] + bb[c]);
        }
        *(short8*)(nf + (size_t)i*512 + lane*8) = o;
    }
}

// ---------------- launch ----------------

extern "C" void kernel_launch(void* const* d_in, const int* in_sizes, int n_in,
                              void* d_out, int out_size, void* d_ws, size_t ws_size,
                              hipStream_t stream) {
    const float* feats  = (const float*)d_in[0];
    const int*   coords = (const int*)d_in[1];
    const float* conv_w = (const float*)d_in[2];
    const float* conv_b = (const float*)d_in[3];
    const float* ln_g   = (const float*)d_in[4];
    const float* ln_b   = (const float*)d_in[5];
    const float* w1     = (const float*)d_in[6];
    const float* b1     = (const float*)d_in[7];
    const float* w2     = (const float*)d_in[8];
    const float* b2     = (const float*)d_in[9];
    float* out = (float*)d_out;
    char* ws = (char*)d_ws;

    size_t off = 0;
    auto take = [&](size_t bytes) -> void* {
        void* p = ws + off;
        off += (bytes + 1023) & ~(size_t)1023;
        return p;
    };
    int* grid_i   = (int*)take((size_t)GDIM*GDIM2*4);
    u16* wcT      = (u16*)take(27ull*512*512*2);
    u16* w1T      = (u16*)take(2048ull*512*2);
    u16* w2T      = (u16*)take(512ull*2048*2);
    u16* fb       = (u16*)take((NPTS+1ull)*512*2);  // cast feats
    int* srcIdx   = (int*)take(26ull*CAPO*4);
    int* posMap   = (int*)take(26ull*NPTS*4);
    int* blockCnt = (int*)take(26*256*4);
    int* blockOff = (int*)take(26*256*4);
    int* cnt      = (int*)take(26*4);

    const size_t nf_b     = 67108864ull;           // bf16 [N][512]
    const size_t comp13_b = 13ull*CAPO*512*2;      // 245.4 MB
    const size_t hc_b     = 67108864ull;           // bf16 [N][512]
    const size_t slack    = 65536;

    // Layout A: separate nf (fb stays intact -> bf16 residual). Needs +64MB.
    bool sepNF = (off + nf_b + comp13_b + hc_b + slack) <= ws_size;

    u16* nf   = sepNF ? (u16*)take(nf_b) : fb;     // Layout B: nf aliases fb (f32 resid)
    u16* comp = (u16*)take(comp13_b);
    u16* hc   = (u16*)take(hc_b);
    u16* g1   = comp;   // [N][2048] overlays comp(245MB)+hc(64MB): both dead after reduce<1>

    hipMemsetAsync(grid_i, 0xFF, (size_t)GDIM*GDIM2*4, stream);
    hipMemsetAsync(fb + (size_t)NPTS*512, 0, 512*2, stream);

    cast_scatter<<<(NPTS*CCH/8)/256, 256, 0, stream>>>(feats, fb, coords, grid_i);
    transpose_cast<<<dim3(16,16,27), dim3(32,8), 0, stream>>>(conv_w, wcT, 512, 512);
    transpose_cast<<<dim3(64,16,1),  dim3(32,8), 0, stream>>>(w1, w1T, 512, 2048);
    transpose_cast<<<dim3(16,64,1),  dim3(32,8), 0, stream>>>(w2, w2T, 2048, 512);

    count_valid<<<dim3(256,26), 256, 0, stream>>>(coords, grid_i, blockCnt);
    scan_kernel<<<26, 256, 0, stream>>>(blockCnt, blockOff, cnt);
    fill_kernel<<<dim3(256,26), 256, 0, stream>>>(coords, grid_i, blockOff, srcIdx, posMap);

    // center offset (o=13): dense, writes hc bf16 = fb @ W13^T + conv_b
    gemm128<3,4,0,512><<<2048, 256, 0, stream>>>(
        fb, 512, wcT + (13ull << 18), 512, 8, conv_b,
        nullptr, nullptr, nullptr, hc);

    // two passes of 13 non-center offsets: compact GEMM -> gather reduce (no atomics)
    comp_gemm<<<4*TPO1*13, 256, 0, stream>>>(fb, srcIdx, cnt, wcT, comp, 0);
    reduce_kernel<0><<<NPTS/8, 512, 0, stream>>>(comp, posMap, 0, 13, hc, nullptr, nullptr, nullptr);
    comp_gemm<<<4*TPO1*13, 256, 0, stream>>>(fb, srcIdx, cnt, wcT, comp, 13);
    reduce_kernel<1><<<NPTS/8, 512, 0, stream>>>(comp, posMap, 13, 13, hc, ln_g, ln_b, nf);

    // MLP1 fused: one launch over all 2048 hidden cols -> g1 [N][2048] (overlays comp+hc)
    gemm128<1,16,0,2048><<<8192, 256, 0, stream>>>(
        nf, 512, w1T, 512, 8, b1, nullptr, nullptr, nullptr, g1);

    // MLP2 fused: single K=2048 launch, writes out once
    if (sepNF) {
        gemm128<2,4,1,512><<<2048, 256, 0, stream>>>(
            g1, 2048, w2T, 2048, 32, b2, fb, nullptr, out, nullptr);
    } else {
        gemm128<2,4,0,512><<<2048, 256, 0, stream>>>(
            g1, 2048, w2T, 2048, 32, b2, nullptr, feats, out, nullptr);
    }
}